// Round 6
// baseline (959.307 us; speedup 1.0000x reference)
//
#include <hip/hip_runtime.h>
#include <cfloat>

#define ITEMS 64
#define HID   256
#define BLK   1024              // 16 waves; 1 block/CU; each wave owns CHUNK samples
#define HROW  72                // bf16 W row stride (144 B, 16B-aligned, 2-way-free banks)
#define BAND  0.016f            // 2*B ; worst-case |approx-exact| <= 3.9e-3, 2x margin
#define CHUNK 16                // samples per wave-chunk (one 16x16 M-tile)

typedef __attribute__((ext_vector_type(8))) short bf16x8;   // 8 bf16 = 4 VGPRs
typedef __attribute__((ext_vector_type(4))) float f32x4;

#define MFMA(A,B,C) __builtin_amdgcn_mfma_f32_16x16x32_bf16((A),(B),(C),0,0,0)

__global__ __launch_bounds__(BLK, 4) void rochet_fwd(
    const float* __restrict__ val,   // [B, 64]
    const float* __restrict__ W,     // [256, 64]
    const float* __restrict__ w0,    // [256]
    float* __restrict__ alloc,       // [B, 64]
    float* __restrict__ pay,         // [B]
    int batch)
{
    // 36,864 + 36,864 + 8,192 + 1,024 + 1,024 = 83,968 B (one block/CU, 16 waves)
    __shared__ __attribute__((aligned(16))) ushort lWh[HID * HROW];      // bf16 hi(W)
    __shared__ __attribute__((aligned(16))) ushort lWl[HID * HROW];      // bf16 lo(W)
    __shared__ __attribute__((aligned(16))) ushort cmask[(BLK/64) * CHUNK * 16];
    __shared__ float lw0[HID];
    __shared__ int   stage[(BLK/64) * CHUNK];

    const int tid = threadIdx.x;

    // ---- Stage W: truncation-split bf16 hi/lo (exact); w0 ----
    {
        const int r  = tid >> 2;                       // 256 rows, 4 threads/row
        const int hh = (tid & 3) * 16;                 // 16-float quarter-row
        const float4* wg = reinterpret_cast<const float4*>(W + r * ITEMS + hh);
        uint* ph = reinterpret_cast<uint*>(&lWh[r * HROW + hh]);
        uint* pl = reinterpret_cast<uint*>(&lWl[r * HROW + hh]);
        #pragma unroll
        for (int q = 0; q < 4; ++q) {
            float4 w4 = wg[q];
            float f[4] = {w4.x, w4.y, w4.z, w4.w};
            #pragma unroll
            for (int p = 0; p < 2; ++p) {
                uint  b0 = __float_as_uint(f[2*p+0]);
                uint  b1 = __float_as_uint(f[2*p+1]);
                float r0 = f[2*p+0] - __uint_as_float(b0 & 0xffff0000u);  // exact
                float r1 = f[2*p+1] - __uint_as_float(b1 & 0xffff0000u);  // exact
                ph[2*q+p] = (b0 >> 16) | (b1 & 0xffff0000u);
                pl[2*q+p] = (__float_as_uint(r0) >> 16) | (__float_as_uint(r1) & 0xffff0000u);
            }
        }
        if (tid < HID) lw0[tid] = w0[tid];
    }
    __syncthreads();
    // Everything below is wave-local: no further block barriers.

    const int wave = tid >> 6, lane = tid & 63;
    const int c = lane & 15, g = lane >> 4;            // MFMA lane decomposition
    const int nchunks = (batch + CHUNK - 1) / CHUNK;
    const int nw = gridDim.x * (BLK / 64);             // total waves (persistent grid)
    const int tb = c * HROW + g * 8;                   // B-frag base element in lWh/lWl

    for (int ch = blockIdx.x * (BLK / 64) + wave; ch < nchunks; ch += nw) {
        const int ms = ch * CHUNK;                     // this wave's first sample

        // ---- A fragments: val row ms+c, k-elems 8g..8g+7 (+32), bf16 hi/lo ----
        bf16x8 Ah[2], Al[2];
        {
            int srow = ms + c;
            if (srow >= batch) srow = batch - 1;       // safe duplicate; result unused
            const float4* vp = reinterpret_cast<const float4*>(val + (size_t)srow * ITEMS);
            #pragma unroll
            for (int ko = 0; ko < 2; ++ko) {
                float4 fa = vp[ko * 8 + 2 * g + 0];
                float4 fb = vp[ko * 8 + 2 * g + 1];
                float f[8] = {fa.x, fa.y, fa.z, fa.w, fb.x, fb.y, fb.z, fb.w};
                #pragma unroll
                for (int i = 0; i < 8; ++i) {
                    uint  b  = __float_as_uint(f[i]);
                    float rr = f[i] - __uint_as_float(b & 0xffff0000u);   // exact
                    Ah[ko][i] = (short)(b >> 16);
                    Al[ko][i] = (short)(__float_as_uint(rr) >> 16);
                }
            }
        }

        // ---- single MFMA pass; keep all 16 tile accumulators in registers ----
        // slot r -> sample-in-chunk 4g+r; lane c -> hidden col t*16+c
        f32x4 acc[16];
        #pragma unroll
        for (int t = 0; t < 16; ++t) {
            bf16x8 bh0 = *reinterpret_cast<const bf16x8*>(&lWh[tb + t * 16 * HROW]);
            bf16x8 bh1 = *reinterpret_cast<const bf16x8*>(&lWh[tb + t * 16 * HROW + 32]);
            bf16x8 bl0 = *reinterpret_cast<const bf16x8*>(&lWl[tb + t * 16 * HROW]);
            bf16x8 bl1 = *reinterpret_cast<const bf16x8*>(&lWl[tb + t * 16 * HROW + 32]);
            f32x4 a = {0.f, 0.f, 0.f, 0.f};
            a = MFMA(Al[0], bh0, a);
            a = MFMA(Ah[0], bl0, a);
            a = MFMA(Ah[0], bh0, a);
            a = MFMA(Al[1], bh1, a);
            a = MFMA(Ah[1], bl1, a);
            a = MFMA(Ah[1], bh1, a);
            acc[t] = a;
        }

        // ---- fold +w0 (one separately-rounded add), track per-slot max ----
        float m1[4] = {-FLT_MAX, -FLT_MAX, -FLT_MAX, -FLT_MAX};
        #pragma unroll
        for (int t = 0; t < 16; ++t) {
            float w0c = lw0[t * 16 + c];
            #pragma unroll
            for (int r = 0; r < 4; ++r) {
                acc[t][r] += w0c;
                m1[r] = fmaxf(m1[r], acc[t][r]);
            }
        }
        // reduce over the 16 column-lanes (same g) -> all lanes hold slot maxima
        #pragma unroll
        for (int d = 1; d < 16; d <<= 1) {
            #pragma unroll
            for (int r = 0; r < 4; ++r)
                m1[r] = fmaxf(m1[r], __shfl_xor(m1[r], d));
        }
        #pragma unroll
        for (int r = 0; r < 4; ++r) m1[r] -= BAND;     // threshold, in place

        // ---- candidate bitmap straight from the stored accumulators ----
        uint cm[4] = {0, 0, 0, 0};
        #pragma unroll
        for (int t = 0; t < 16; ++t) {
            #pragma unroll
            for (int r = 0; r < 4; ++r)
                if (acc[t][r] >= m1[r]) cm[r] |= (1u << t);
        }
        // scatter bitmap: row = sample-in-chunk (4g+r), col = this lane's c
        #pragma unroll
        for (int r = 0; r < 4; ++r)
            cmask[(wave * CHUNK + 4 * g + r) * 16 + c] = (ushort)cm[r];
        asm volatile("s_waitcnt lgkmcnt(0)" ::: "memory");   // wave-local handoff

        // ---- owner lanes (lane < 16): exact fp32 rescore of candidates only ----
        // Guarantee: candidate set contains the exact argmax; all non-candidates
        // are strictly below the exact winner. W read from global (same bits).
        const int s  = ms + lane;
        const int sc = (s < batch) ? s : (batch - 1);
        const float4* vg = reinterpret_cast<const float4*>(val + (size_t)sc * ITEMS);

        float hbest = -FLT_MAX;
        int   jbest = 0;
        if (lane < CHUNK) {
            const uint* crow = reinterpret_cast<const uint*>(&cmask[(wave * CHUNK + lane) * 16]);
            #pragma unroll
            for (int q = 0; q < 8; ++q) {
                uint e = crow[q];                       // cols 2q (lo16) / 2q+1 (hi16)
                while (e) {
                    int b = __ffs(e) - 1;
                    e &= e - 1;
                    int j = ((b & 15) << 4) + 2 * q + (b >> 4);   // j = t*16 + c
                    const float4* wr = reinterpret_cast<const float4*>(W + j * ITEMS);
                    float aa = 0.0f;                    // exact sequential fma chain
                    #pragma unroll
                    for (int k = 0; k < 16; ++k) {
                        float4 t4 = wr[k];
                        float4 vv = vg[k];
                        aa = fmaf(t4.x, vv.x, aa); aa = fmaf(t4.y, vv.y, aa);
                        aa = fmaf(t4.z, vv.z, aa); aa = fmaf(t4.w, vv.w, aa);
                    }
                    float h = aa + lw0[j];              // one separately-rounded +w0
                    if (h > hbest || (h == hbest && j < jbest)) { hbest = h; jbest = j; }
                }
            }
        }

        const bool pos = hbest > 0.0f;
        if (lane < CHUNK && s < batch) {
            float p = 0.0f;
            const float4* wr = reinterpret_cast<const float4*>(W + jbest * ITEMS);
            #pragma unroll
            for (int k = 0; k < 16; ++k) {
                float4 t4 = wr[k];                      // L1-hot (just read above)
                float4 vv = vg[k];
                float ox = fminf(fmaxf(t4.x, 0.0f), 1.0f);
                float oy = fminf(fmaxf(t4.y, 0.0f), 1.0f);
                float oz = fminf(fmaxf(t4.z, 0.0f), 1.0f);
                float ow = fminf(fmaxf(t4.w, 0.0f), 1.0f);
                if (!pos) { ox = oy = oz = ow = 0.0f; }
                p = fmaf(ox, vv.x, p);
                p = fmaf(oy, vv.y, p);
                p = fmaf(oz, vv.z, p);
                p = fmaf(ow, vv.w, p);
            }
            p -= fmaxf(hbest, 0.0f);
            pay[s] = fmaxf(p, 0.0f);
        }

        // ---- wave-cooperative, fully-coalesced alloc store (W from global/L1) ----
        if (lane < CHUNK) stage[wave * CHUNK + lane] = jbest | (pos ? 0x100 : 0);
        asm volatile("s_waitcnt lgkmcnt(0)" ::: "memory");   // wave-local handoff
        const float4* Wg4 = reinterpret_cast<const float4*>(W);
        float4* allocF4 = reinterpret_cast<float4*>(alloc) + (size_t)ms * (ITEMS / 4);
        #pragma unroll
        for (int k = 0; k < 4; ++k) {
            int f = k * 64 + lane;                     // float4 index in 4 KB tile
            int t = f >> 4, cc = f & 15;
            if (ms + t < batch) {
                int   pk = stage[wave * CHUNK + t];
                int   ti = pk & 0xff;
                bool  tp = (pk & 0x100) != 0;
                float4 wv = Wg4[ti * (ITEMS / 4) + cc];
                float4 o;
                o.x = tp ? fminf(fmaxf(wv.x, 0.0f), 1.0f) : 0.0f;
                o.y = tp ? fminf(fmaxf(wv.y, 0.0f), 1.0f) : 0.0f;
                o.z = tp ? fminf(fmaxf(wv.z, 0.0f), 1.0f) : 0.0f;
                o.w = tp ? fminf(fmaxf(wv.w, 0.0f), 1.0f) : 0.0f;
                allocF4[f] = o;
            }
        }
    }
}

extern "C" void kernel_launch(void* const* d_in, const int* in_sizes, int n_in,
                              void* d_out, int out_size, void* d_ws, size_t ws_size,
                              hipStream_t stream) {
    const float* val = (const float*)d_in[0];   // [B,64]
    const float* W   = (const float*)d_in[1];   // [256,64]
    const float* w0  = (const float*)d_in[2];   // [256]
    float* out = (float*)d_out;
    int batch = in_sizes[0] / ITEMS;            // 1,000,000
    float* alloc = out;                         // [B,64]
    float* pay   = out + (size_t)batch * ITEMS; // [B]

    // Persistent grid: 1024-thread block, 83,968 B LDS -> 1 block/CU, 16 waves/CU.
    int nchunks = (batch + CHUNK - 1) / CHUNK;
    int grid = (nchunks + (BLK / 64) - 1) / (BLK / 64);
    if (grid > 256) grid = 256;
    rochet_fwd<<<grid, BLK, 0, stream>>>(val, W, w0, alloc, pay, batch);
}

// Round 7
// 940.568 us; speedup vs baseline: 1.0199x; 1.0199x over previous
//
#include <hip/hip_runtime.h>
#include <cfloat>

#define ITEMS 64
#define HID   256
#define BLK   512               // 8 waves; 2 blocks/CU (LDS 79,360 B); CHUNK samples/wave
#define HROW  72                // bf16 W row stride (144 B, 16B-aligned, 2-way-free banks)
#define BAND  0.016f            // 2*B ; worst-case |approx-exact| <= 3.9e-3, 2x margin
#define CHUNK 16                // samples per wave-chunk (one 16x16 M-tile)

typedef __attribute__((ext_vector_type(8))) short bf16x8;   // 8 bf16 = 4 VGPRs
typedef __attribute__((ext_vector_type(4))) float f32x4;

#define MFMA(A,B,C) __builtin_amdgcn_mfma_f32_16x16x32_bf16((A),(B),(C),0,0,0)

__global__ __launch_bounds__(BLK, 4) void rochet_fwd(
    const float* __restrict__ val,   // [B, 64]
    const float* __restrict__ W,     // [256, 64]
    const float* __restrict__ w0,    // [256]
    float* __restrict__ alloc,       // [B, 64]
    float* __restrict__ pay,         // [B]
    int batch)
{
    // 36,864 + 36,864 + 4,096 + 1,024 + 512 = 79,360 B -> 2 blocks/CU (160 KiB pool)
    __shared__ __attribute__((aligned(16))) ushort lWh[HID * HROW];      // bf16 hi(W)
    __shared__ __attribute__((aligned(16))) ushort lWl[HID * HROW];      // bf16 lo(W)
    __shared__ __attribute__((aligned(16))) ushort cmask[(BLK/64) * CHUNK * 16];
    __shared__ float lw0[HID];
    __shared__ int   stage[(BLK/64) * CHUNK];

    const int tid = threadIdx.x;

    // ---- Stage W: truncation-split bf16 hi/lo (exact); w0 ----
    {
        const int r  = tid >> 1;                       // 256 rows, 2 threads/row
        const int hh = (tid & 1) * 32;                 // 32-float half-row
        const float4* wg = reinterpret_cast<const float4*>(W + r * ITEMS + hh);
        uint* ph = reinterpret_cast<uint*>(&lWh[r * HROW + hh]);
        uint* pl = reinterpret_cast<uint*>(&lWl[r * HROW + hh]);
        #pragma unroll
        for (int q = 0; q < 8; ++q) {
            float4 w4 = wg[q];
            float f[4] = {w4.x, w4.y, w4.z, w4.w};
            #pragma unroll
            for (int p = 0; p < 2; ++p) {
                uint  b0 = __float_as_uint(f[2*p+0]);
                uint  b1 = __float_as_uint(f[2*p+1]);
                float r0 = f[2*p+0] - __uint_as_float(b0 & 0xffff0000u);  // exact
                float r1 = f[2*p+1] - __uint_as_float(b1 & 0xffff0000u);  // exact
                ph[2*q+p] = (b0 >> 16) | (b1 & 0xffff0000u);
                pl[2*q+p] = (__float_as_uint(r0) >> 16) | (__float_as_uint(r1) & 0xffff0000u);
            }
        }
        if (tid < HID) lw0[tid] = w0[tid];
    }
    __syncthreads();
    // Everything below is wave-local: no further block barriers.

    const int wave = tid >> 6, lane = tid & 63;
    const int c = lane & 15, g = lane >> 4;            // MFMA lane decomposition
    const int nchunks = (batch + CHUNK - 1) / CHUNK;
    const int nw = gridDim.x * (BLK / 64);             // total waves (persistent grid)
    const int tb = c * HROW + g * 8;                   // B-frag base element in lWh/lWl

    for (int ch = blockIdx.x * (BLK / 64) + wave; ch < nchunks; ch += nw) {
        const int ms = ch * CHUNK;                     // this wave's first sample

        // ---- A fragments: val row ms+c, k-elems 8g..8g+7 (+32), bf16 hi/lo ----
        bf16x8 Ah[2], Al[2];
        {
            int srow = ms + c;
            if (srow >= batch) srow = batch - 1;       // safe duplicate; result unused
            const float4* vp = reinterpret_cast<const float4*>(val + (size_t)srow * ITEMS);
            #pragma unroll
            for (int ko = 0; ko < 2; ++ko) {
                float4 fa = vp[ko * 8 + 2 * g + 0];
                float4 fb = vp[ko * 8 + 2 * g + 1];
                float f[8] = {fa.x, fa.y, fa.z, fa.w, fb.x, fb.y, fb.z, fb.w};
                #pragma unroll
                for (int i = 0; i < 8; ++i) {
                    uint  b  = __float_as_uint(f[i]);
                    float rr = f[i] - __uint_as_float(b & 0xffff0000u);   // exact
                    Ah[ko][i] = (short)(b >> 16);
                    Al[ko][i] = (short)(__float_as_uint(rr) >> 16);
                }
            }
        }

        // ---- single MFMA pass; keep all 16 tile accumulators in registers ----
        // slot r -> sample-in-chunk 4g+r; lane c -> hidden col t*16+c
        f32x4 acc[16];
        #pragma unroll
        for (int t = 0; t < 16; ++t) {
            bf16x8 bh0 = *reinterpret_cast<const bf16x8*>(&lWh[tb + t * 16 * HROW]);
            bf16x8 bh1 = *reinterpret_cast<const bf16x8*>(&lWh[tb + t * 16 * HROW + 32]);
            bf16x8 bl0 = *reinterpret_cast<const bf16x8*>(&lWl[tb + t * 16 * HROW]);
            bf16x8 bl1 = *reinterpret_cast<const bf16x8*>(&lWl[tb + t * 16 * HROW + 32]);
            f32x4 a = {0.f, 0.f, 0.f, 0.f};
            a = MFMA(Al[0], bh0, a);
            a = MFMA(Ah[0], bl0, a);
            a = MFMA(Ah[0], bh0, a);
            a = MFMA(Al[1], bh1, a);
            a = MFMA(Ah[1], bl1, a);
            a = MFMA(Ah[1], bh1, a);
            acc[t] = a;
        }

        // ---- fold +w0 (one separately-rounded add), track per-slot max ----
        float m1[4] = {-FLT_MAX, -FLT_MAX, -FLT_MAX, -FLT_MAX};
        #pragma unroll
        for (int t = 0; t < 16; ++t) {
            float w0c = lw0[t * 16 + c];
            #pragma unroll
            for (int r = 0; r < 4; ++r) {
                acc[t][r] += w0c;
                m1[r] = fmaxf(m1[r], acc[t][r]);
            }
        }
        // reduce over the 16 column-lanes (same g) -> all lanes hold slot maxima
        #pragma unroll
        for (int d = 1; d < 16; d <<= 1) {
            #pragma unroll
            for (int r = 0; r < 4; ++r)
                m1[r] = fmaxf(m1[r], __shfl_xor(m1[r], d));
        }
        #pragma unroll
        for (int r = 0; r < 4; ++r) m1[r] -= BAND;     // threshold, in place

        // ---- candidate bitmap straight from the stored accumulators ----
        uint cm[4] = {0, 0, 0, 0};
        #pragma unroll
        for (int t = 0; t < 16; ++t) {
            #pragma unroll
            for (int r = 0; r < 4; ++r)
                if (acc[t][r] >= m1[r]) cm[r] |= (1u << t);
        }
        // scatter bitmap: row = sample-in-chunk (4g+r), col = this lane's c
        #pragma unroll
        for (int r = 0; r < 4; ++r)
            cmask[(wave * CHUNK + 4 * g + r) * 16 + c] = (ushort)cm[r];
        asm volatile("s_waitcnt lgkmcnt(0)" ::: "memory");   // wave-local handoff

        // ---- owner lanes (lane < 16): exact fp32 rescore of candidates only ----
        // Guarantee: candidate set contains the exact argmax; all non-candidates
        // are strictly below the exact winner. W read from global (same bits).
        const int s  = ms + lane;
        const int sc = (s < batch) ? s : (batch - 1);
        const float4* vg = reinterpret_cast<const float4*>(val + (size_t)sc * ITEMS);

        float hbest = -FLT_MAX;
        int   jbest = 0;
        if (lane < CHUNK) {
            const uint* crow = reinterpret_cast<const uint*>(&cmask[(wave * CHUNK + lane) * 16]);
            #pragma unroll
            for (int q = 0; q < 8; ++q) {
                uint e = crow[q];                       // cols 2q (lo16) / 2q+1 (hi16)
                while (e) {
                    int b = __ffs(e) - 1;
                    e &= e - 1;
                    int j = ((b & 15) << 4) + 2 * q + (b >> 4);   // j = t*16 + c
                    const float4* wr = reinterpret_cast<const float4*>(W + j * ITEMS);
                    float aa = 0.0f;                    // exact sequential fma chain
                    #pragma unroll
                    for (int k = 0; k < 16; ++k) {
                        float4 t4 = wr[k];
                        float4 vv = vg[k];
                        aa = fmaf(t4.x, vv.x, aa); aa = fmaf(t4.y, vv.y, aa);
                        aa = fmaf(t4.z, vv.z, aa); aa = fmaf(t4.w, vv.w, aa);
                    }
                    float h = aa + lw0[j];              // one separately-rounded +w0
                    if (h > hbest || (h == hbest && j < jbest)) { hbest = h; jbest = j; }
                }
            }
        }

        const bool pos = hbest > 0.0f;
        if (lane < CHUNK && s < batch) {
            float p = 0.0f;
            const float4* wr = reinterpret_cast<const float4*>(W + jbest * ITEMS);
            #pragma unroll
            for (int k = 0; k < 16; ++k) {
                float4 t4 = wr[k];                      // L1-hot (just read above)
                float4 vv = vg[k];
                float ox = fminf(fmaxf(t4.x, 0.0f), 1.0f);
                float oy = fminf(fmaxf(t4.y, 0.0f), 1.0f);
                float oz = fminf(fmaxf(t4.z, 0.0f), 1.0f);
                float ow = fminf(fmaxf(t4.w, 0.0f), 1.0f);
                if (!pos) { ox = oy = oz = ow = 0.0f; }
                p = fmaf(ox, vv.x, p);
                p = fmaf(oy, vv.y, p);
                p = fmaf(oz, vv.z, p);
                p = fmaf(ow, vv.w, p);
            }
            p -= fmaxf(hbest, 0.0f);
            pay[s] = fmaxf(p, 0.0f);
        }

        // ---- wave-cooperative, fully-coalesced alloc store (W from global/L1) ----
        if (lane < CHUNK) stage[wave * CHUNK + lane] = jbest | (pos ? 0x100 : 0);
        asm volatile("s_waitcnt lgkmcnt(0)" ::: "memory");   // wave-local handoff
        const float4* Wg4 = reinterpret_cast<const float4*>(W);
        float4* allocF4 = reinterpret_cast<float4*>(alloc) + (size_t)ms * (ITEMS / 4);
        #pragma unroll
        for (int k = 0; k < 4; ++k) {
            int f = k * 64 + lane;                     // float4 index in 4 KB tile
            int t = f >> 4, cc = f & 15;
            if (ms + t < batch) {
                int   pk = stage[wave * CHUNK + t];
                int   ti = pk & 0xff;
                bool  tp = (pk & 0x100) != 0;
                float4 wv = Wg4[ti * (ITEMS / 4) + cc];
                float4 o;
                o.x = tp ? fminf(fmaxf(wv.x, 0.0f), 1.0f) : 0.0f;
                o.y = tp ? fminf(fmaxf(wv.y, 0.0f), 1.0f) : 0.0f;
                o.z = tp ? fminf(fmaxf(wv.z, 0.0f), 1.0f) : 0.0f;
                o.w = tp ? fminf(fmaxf(wv.w, 0.0f), 1.0f) : 0.0f;
                allocF4[f] = o;
            }
        }
    }
}

extern "C" void kernel_launch(void* const* d_in, const int* in_sizes, int n_in,
                              void* d_out, int out_size, void* d_ws, size_t ws_size,
                              hipStream_t stream) {
    const float* val = (const float*)d_in[0];   // [B,64]
    const float* W   = (const float*)d_in[1];   // [256,64]
    const float* w0  = (const float*)d_in[2];   // [256]
    float* out = (float*)d_out;
    int batch = in_sizes[0] / ITEMS;            // 1,000,000
    float* alloc = out;                         // [B,64]
    float* pay   = out + (size_t)batch * ITEMS; // [B]

    // Persistent grid: 512-thread blocks, 79,360 B LDS -> 2 blocks/CU, 16 waves/CU.
    int nchunks = (batch + CHUNK - 1) / CHUNK;
    int grid = (nchunks + (BLK / 64) - 1) / (BLK / 64);
    if (grid > 512) grid = 512;
    rochet_fwd<<<grid, BLK, 0, stream>>>(val, W, w0, alloc, pay, batch);
}